// Round 1
// baseline (335.975 us; speedup 1.0000x reference)
//
#include <hip/hip_runtime.h>

#define D_DIM 256
#define K_CODES 1024
#define N_TOTAL 32768

// ---------------------------------------------------------------------------
// Kernel: z2[n] = sum_d z[n,d]^2.   z_e layout: [b][d][gh*gw] = [b][d][nl]
// n = b*1024 + nl ; element (n,d) at z + b*262144 + d*1024 + nl
// ---------------------------------------------------------------------------
__global__ __launch_bounds__(256) void k_z2(const float* __restrict__ z,
                                            float* __restrict__ z2) {
    int n = blockIdx.x * 256 + threadIdx.x;   // 128 blocks cover 32768
    int b = n >> 10, nl = n & 1023;
    const float* p = z + (size_t)b * (D_DIM * 1024) + nl;
    float s = 0.f;
#pragma unroll 8
    for (int d = 0; d < D_DIM; ++d) {
        float v = p[(size_t)d * 1024];
        s = fmaf(v, v, s);
    }
    z2[n] = s;
}

// ---------------------------------------------------------------------------
// Kernel: e2[k] = sum_d emb[k,d]^2  (emb row-major 1024x256)
// ---------------------------------------------------------------------------
__global__ __launch_bounds__(256) void k_e2(const float* __restrict__ e,
                                            float* __restrict__ e2) {
    int k = blockIdx.x * 256 + threadIdx.x;   // 4 blocks
    const float4* p = (const float4*)(e + (size_t)k * D_DIM);
    float s = 0.f;
#pragma unroll 4
    for (int c = 0; c < D_DIM / 4; ++c) {
        float4 v = p[c];
        s = fmaf(v.x, v.x, s); s = fmaf(v.y, v.y, s);
        s = fmaf(v.z, v.z, s); s = fmaf(v.w, v.w, s);
    }
    e2[k] = s;
}

// ---------------------------------------------------------------------------
// Kernel: fused fp32 GEMM (ze = z . emb^T) + argmin over codes, replicating
// the reference rounding: dist = fl( fl(z2 + e2[k]) - 2*ze )  (2*ze exact)
// Block: 256 thr; tile 64 rows x 128 codes per chunk; 8 chunks; d staged 32.
// Thread (tk = t&15, tr = t>>4): 4 rows x 8 codes.
// ---------------------------------------------------------------------------
__global__ __launch_bounds__(256) void k_argmin(const float* __restrict__ z,
                                                const float* __restrict__ e,
                                                const float* __restrict__ z2,
                                                const float* __restrict__ e2,
                                                float* __restrict__ outIdx,
                                                int* __restrict__ wsIdx) {
    __shared__ float Zs[32][64];    // [dd][row]   8 KB
    __shared__ float Es[32][128];   // [dd][code] 16 KB
    __shared__ float rbD[64][16];   //            4 KB
    __shared__ int   rbI[64][16];   //            4 KB

    const int t  = threadIdx.x;
    const int tk = t & 15;
    const int tr = t >> 4;
    const int n0 = blockIdx.x * 64;          // global row base
    const int b  = n0 >> 10;
    const int nl0 = n0 & 1023;
    const float* zb = z + (size_t)b * (D_DIM * 1024) + nl0;

    float bD[4];
    int   bI[4];
#pragma unroll
    for (int i = 0; i < 4; ++i) { bD[i] = 3.4e38f; bI[i] = 0; }

    float z2r[4];
#pragma unroll
    for (int i = 0; i < 4; ++i) z2r[i] = z2[n0 + tr * 4 + i];

    for (int kc = 0; kc < 8; ++kc) {
        const int k0 = kc * 128;
        float acc[4][8];
#pragma unroll
        for (int i = 0; i < 4; ++i)
#pragma unroll
            for (int j = 0; j < 8; ++j) acc[i][j] = 0.f;

        for (int dsb = 0; dsb < 8; ++dsb) {
            const int d0 = dsb * 32;
            // stage Z tile: 32 d x 64 n  (global: n contiguous -> coalesced)
#pragma unroll
            for (int j = 0; j < 2; ++j) {
                int flat = t + 256 * j;          // [0,512)
                int dd = flat >> 4;              // 0..31
                int c4 = flat & 15;              // 16 float4 per d-row
                float4 v = *(const float4*)(zb + (size_t)(d0 + dd) * 1024 + c4 * 4);
                *(float4*)&Zs[dd][c4 * 4] = v;
            }
            // stage E tile transposed: Es[dd][k] = emb[k0+k][d0+dd]
#pragma unroll
            for (int j = 0; j < 4; ++j) {
                int flat = t + 256 * j;          // [0,1024)
                int kk = flat >> 3;              // 0..127
                int c4 = flat & 7;               // 8 float4 over 32 d
                float4 v = *(const float4*)(e + (size_t)(k0 + kk) * D_DIM + d0 + c4 * 4);
                Es[c4 * 4 + 0][kk] = v.x;
                Es[c4 * 4 + 1][kk] = v.y;
                Es[c4 * 4 + 2][kk] = v.z;
                Es[c4 * 4 + 3][kk] = v.w;
            }
            __syncthreads();
#pragma unroll 8
            for (int dd = 0; dd < 32; ++dd) {
                float4 zf = *(const float4*)&Zs[dd][tr * 4];
                float4 ea = *(const float4*)&Es[dd][tk * 8];
                float4 eb = *(const float4*)&Es[dd][tk * 8 + 4];
                float zz[4] = { zf.x, zf.y, zf.z, zf.w };
                float ee[8] = { ea.x, ea.y, ea.z, ea.w, eb.x, eb.y, eb.z, eb.w };
#pragma unroll
                for (int i = 0; i < 4; ++i)
#pragma unroll
                    for (int j = 0; j < 8; ++j)
                        acc[i][j] = fmaf(zz[i], ee[j], acc[i][j]);
            }
            __syncthreads();
        }

        // fold this chunk into the running argmin (k ascending -> first-min tiebreak)
        float e2r[8];
#pragma unroll
        for (int j = 0; j < 8; ++j) e2r[j] = e2[k0 + tk * 8 + j];
#pragma unroll
        for (int i = 0; i < 4; ++i) {
#pragma unroll
            for (int j = 0; j < 8; ++j) {
                float t1 = z2r[i] + e2r[j];            // fl(z2 + e2)
                float dist = fmaf(-2.0f, acc[i][j], t1); // fl(t1 - 2*ze), 2*ze exact
                if (dist < bD[i]) { bD[i] = dist; bI[i] = k0 + tk * 8 + j; }
            }
        }
    }

    // cross-thread reduce: 16 tk-threads share each row; lexicographic (dist, idx)
#pragma unroll
    for (int i = 0; i < 4; ++i) {
        rbD[tr * 4 + i][tk] = bD[i];
        rbI[tr * 4 + i][tk] = bI[i];
    }
    __syncthreads();
    if (t < 64) {
        float bd = rbD[t][0];
        int   bi = rbI[t][0];
#pragma unroll
        for (int m = 1; m < 16; ++m) {
            float d = rbD[t][m];
            int  ii = rbI[t][m];
            if (d < bd || (d == bd && ii < bi)) { bd = d; bi = ii; }
        }
        outIdx[n0 + t] = (float)bi;
        wsIdx[n0 + t]  = bi;
    }
}

// ---------------------------------------------------------------------------
// Kernel: epilogue — z_q gather, straight-through output, loss partial sums.
// Block: 256 thr handles 64 rows x 256 d. zq staged in LDS (XOR-swizzled).
// out = z + (zq - z)  (replicates reference fp path; no mul -> no contraction)
// ---------------------------------------------------------------------------
__global__ __launch_bounds__(256) void k_epilogue(const float* __restrict__ z,
                                                  const float* __restrict__ e,
                                                  const int* __restrict__ wsIdx,
                                                  float* __restrict__ outZ,
                                                  float* __restrict__ lossAcc) {
    __shared__ float4 zq4[64][64];   // (i, c4) stored at zq4[i][c4 ^ (i&7)]
    __shared__ int idxs[64];
    const int t = threadIdx.x;
    const int n0 = blockIdx.x * 64;
    const int b = n0 >> 10, nl0 = n0 & 1023;

    if (t < 64) idxs[t] = wsIdx[n0 + t];
    __syncthreads();

    // gather emb rows into LDS (per row: 1 KB contiguous read by 64 lanes)
#pragma unroll
    for (int j = 0; j < 16; ++j) {
        int flat = j * 256 + t;
        int i  = flat >> 6;          // row 0..63
        int c4 = flat & 63;          // float4 col
        float4 v = *(const float4*)(e + (size_t)idxs[i] * D_DIM + c4 * 4);
        zq4[i][c4 ^ (i & 7)] = v;
    }
    __syncthreads();

    const int i  = t & 63;           // row
    const int dg = t >> 6;           // d-group 0..3 (64 d each)
    const float* zp = z   + (size_t)b * (D_DIM * 1024) + nl0 + i;
    float*       op = outZ + (size_t)b * (D_DIM * 1024) + nl0 + i;
    float s = 0.f;
#pragma unroll 4
    for (int c = 0; c < 16; ++c) {
        int c4 = dg * 16 + c;
        float4 q = zq4[i][c4 ^ (i & 7)];
        int d = c4 * 4;
        float zv, df;
        zv = zp[(size_t)(d + 0) * 1024]; df = q.x - zv; s = fmaf(df, df, s); op[(size_t)(d + 0) * 1024] = zv + df;
        zv = zp[(size_t)(d + 1) * 1024]; df = q.y - zv; s = fmaf(df, df, s); op[(size_t)(d + 1) * 1024] = zv + df;
        zv = zp[(size_t)(d + 2) * 1024]; df = q.z - zv; s = fmaf(df, df, s); op[(size_t)(d + 2) * 1024] = zv + df;
        zv = zp[(size_t)(d + 3) * 1024]; df = q.w - zv; s = fmaf(df, df, s); op[(size_t)(d + 3) * 1024] = zv + df;
    }
    // wave reduce then one atomic per wave
#pragma unroll
    for (int off = 32; off > 0; off >>= 1) s += __shfl_down(s, off, 64);
    if ((t & 63) == 0) atomicAdd(lossAcc, s);
}

// ---------------------------------------------------------------------------
// Kernel: finalize vq_loss = m + 0.25*m, m = S / (N*D)
// ---------------------------------------------------------------------------
__global__ void k_final(const float* __restrict__ lossAcc,
                        float* __restrict__ outLoss) {
    float m = lossAcc[0] * (1.0f / 8388608.0f);
    outLoss[0] = m + 0.25f * m;
}

// ---------------------------------------------------------------------------
extern "C" void kernel_launch(void* const* d_in, const int* in_sizes, int n_in,
                              void* d_out, int out_size, void* d_ws, size_t ws_size,
                              hipStream_t stream) {
    const float* z = (const float*)d_in[0];   // (32,256,32,32)
    const float* e = (const float*)d_in[1];   // (1024,256)
    float* out     = (float*)d_out;
    float* outIdx  = out + 8388608;           // 32768 floats
    float* outLoss = out + 8421376;           // 1 float

    float* z2      = (float*)d_ws;            // 32768 f
    float* e2      = z2 + 32768;              // 1024 f
    int*   wsIdx   = (int*)(e2 + 1024);       // 32768 i
    float* lossAcc = (float*)(wsIdx + 32768); // 1 f

    hipMemsetAsync(lossAcc, 0, sizeof(float), stream);
    k_z2<<<128, 256, 0, stream>>>(z, z2);
    k_e2<<<4, 256, 0, stream>>>(e, e2);
    k_argmin<<<512, 256, 0, stream>>>(z, e, z2, e2, outIdx, wsIdx);
    k_epilogue<<<512, 256, 0, stream>>>(z, e, wsIdx, out, lossAcc);
    k_final<<<1, 1, 0, stream>>>(lossAcc, outLoss);
}

// Round 2
// 277.789 us; speedup vs baseline: 1.2095x; 1.2095x over previous
//
#include <hip/hip_runtime.h>

#define D_DIM 256
#define K_CODES 1024
#define N_TOTAL 32768

// ---------------------------------------------------------------------------
// z2[n] = sum_d z[n,d]^2  (ascending-d chain — DO NOT CHANGE: rounding-exact)
// z_e layout: [b][d][nl], element (n,d) at z + b*262144 + d*1024 + nl
// ---------------------------------------------------------------------------
__global__ __launch_bounds__(256) void k_z2(const float* __restrict__ z,
                                            float* __restrict__ z2) {
    int n = blockIdx.x * 256 + threadIdx.x;
    int b = n >> 10, nl = n & 1023;
    const float* p = z + (size_t)b * (D_DIM * 1024) + nl;
    float s = 0.f;
#pragma unroll 8
    for (int d = 0; d < D_DIM; ++d) {
        float v = p[(size_t)d * 1024];
        s = fmaf(v, v, s);
    }
    z2[n] = s;
}

// ---------------------------------------------------------------------------
// e2[k] = sum_d emb[k,d]^2  (ascending-d chain)
// ---------------------------------------------------------------------------
__global__ __launch_bounds__(256) void k_e2(const float* __restrict__ e,
                                            float* __restrict__ e2) {
    int k = blockIdx.x * 256 + threadIdx.x;
    const float4* p = (const float4*)(e + (size_t)k * D_DIM);
    float s = 0.f;
#pragma unroll 4
    for (int c = 0; c < D_DIM / 4; ++c) {
        float4 v = p[c];
        s = fmaf(v.x, v.x, s); s = fmaf(v.y, v.y, s);
        s = fmaf(v.z, v.z, s); s = fmaf(v.w, v.w, s);
    }
    e2[k] = s;
}

// ---------------------------------------------------------------------------
// ET[d][k] = E[k][d]  — 32x32 LDS-tiled transpose, 1 MB total
// grid: 32 k-tiles x 8 d-tiles = 256 blocks, 256 thr
// ---------------------------------------------------------------------------
__global__ __launch_bounds__(256) void k_tr(const float* __restrict__ e,
                                            float* __restrict__ et) {
    __shared__ float tile[32][33];
    const int t = threadIdx.x;
    const int k0 = (blockIdx.x & 31) * 32;
    const int d0 = (blockIdx.x >> 5) * 32;
    {
        int kk = t >> 3, c4 = (t & 7) * 4;
        float4 v = *(const float4*)(e + (size_t)(k0 + kk) * D_DIM + d0 + c4);
        tile[c4 + 0][kk] = v.x; tile[c4 + 1][kk] = v.y;
        tile[c4 + 2][kk] = v.z; tile[c4 + 3][kk] = v.w;
    }
    __syncthreads();
    {
        int dd = t >> 3, kc4 = (t & 7) * 4;
        float4 o;
        o.x = tile[dd][kc4 + 0]; o.y = tile[dd][kc4 + 1];
        o.z = tile[dd][kc4 + 2]; o.w = tile[dd][kc4 + 3];
        *(float4*)(et + (size_t)(d0 + dd) * K_CODES + k0 + kc4) = o;
    }
}

// ---------------------------------------------------------------------------
// Main: fp32 GEMM tile (128 rows x 128 codes) + per-block argmin, K split 8x.
// grid = 256 row-blocks x 8 code-blocks = 2048. Thread tile 8x8.
// Per (n,k): single ascending-d fp32 FMA chain (bit-identical to round 1).
// Partial result merged via packed u64 (distbits<<32 | idx) atomicMin —
// packed min == lexicographic (dist, idx) since dist > 0 here.
// ---------------------------------------------------------------------------
__global__ __launch_bounds__(256, 3) void k_main(const float* __restrict__ z,
                                                 const float* __restrict__ et,
                                                 const float* __restrict__ z2,
                                                 const float* __restrict__ e2,
                                                 unsigned long long* __restrict__ rowKey) {
    __shared__ float Zs[32][128];   // 16 KB
    __shared__ float Es[32][128];   // 16 KB

    const int t  = threadIdx.x;
    const int tk = t & 15;          // code group
    const int tr = t >> 4;          // row group
    const int kc = blockIdx.x & 7;
    const int rb = blockIdx.x >> 3;
    const int n0 = rb * 128;
    const int b  = n0 >> 10;
    const int nl0 = n0 & 1023;
    const int k0 = kc * 128;
    const float* zb = z + (size_t)b * (D_DIM * 1024) + nl0;

    float acc[8][8];
#pragma unroll
    for (int i = 0; i < 8; ++i)
#pragma unroll
        for (int j = 0; j < 8; ++j) acc[i][j] = 0.f;

    for (int dsb = 0; dsb < 8; ++dsb) {
        const int d0 = dsb * 32;
        // stage: both tiles, coalesced float4 global -> b128 LDS, no scatter
#pragma unroll
        for (int j = 0; j < 4; ++j) {
            int flat = t + 256 * j;              // [0,1024)
            int dd = flat >> 5;                  // 0..31
            int c4 = (flat & 31) * 4;            // 0,4,...,124
            *(float4*)&Zs[dd][c4] =
                *(const float4*)(zb + (size_t)(d0 + dd) * 1024 + c4);
            *(float4*)&Es[dd][c4] =
                *(const float4*)(et + (size_t)(d0 + dd) * K_CODES + k0 + c4);
        }
        __syncthreads();
#pragma unroll 4
        for (int dd = 0; dd < 32; ++dd) {
            float4 za = *(const float4*)&Zs[dd][tr * 8];
            float4 zc = *(const float4*)&Zs[dd][tr * 8 + 4];
            float4 ea = *(const float4*)&Es[dd][tk * 8];
            float4 eb = *(const float4*)&Es[dd][tk * 8 + 4];
            float zz[8] = { za.x, za.y, za.z, za.w, zc.x, zc.y, zc.z, zc.w };
            float ee[8] = { ea.x, ea.y, ea.z, ea.w, eb.x, eb.y, eb.z, eb.w };
#pragma unroll
            for (int i = 0; i < 8; ++i)
#pragma unroll
                for (int j = 0; j < 8; ++j)
                    acc[i][j] = fmaf(zz[i], ee[j], acc[i][j]);
        }
        __syncthreads();
    }

    // distances + within-thread argmin (ascending k), identical rounding:
    // t1 = fl(z2 + e2), dist = fl(t1 - 2*ze) via fmaf(-2, ze, t1)
    float z2r[8], e2r[8];
#pragma unroll
    for (int i = 0; i < 8; ++i) z2r[i] = z2[n0 + tr * 8 + i];
#pragma unroll
    for (int j = 0; j < 8; ++j) e2r[j] = e2[k0 + tk * 8 + j];

    unsigned long long bKey[8];
#pragma unroll
    for (int i = 0; i < 8; ++i) bKey[i] = 0xFFFFFFFFFFFFFFFFULL;
#pragma unroll
    for (int i = 0; i < 8; ++i) {
#pragma unroll
        for (int j = 0; j < 8; ++j) {
            float t1 = z2r[i] + e2r[j];
            float dist = fmaf(-2.0f, acc[i][j], t1);
            unsigned long long key =
                ((unsigned long long)__float_as_uint(dist) << 32) |
                (unsigned int)(k0 + tk * 8 + j);
            if (key < bKey[i]) bKey[i] = key;
        }
    }
    // butterfly across the 16 tk lanes (same tr) — min of packed keys
#pragma unroll
    for (int m = 1; m < 16; m <<= 1) {
#pragma unroll
        for (int i = 0; i < 8; ++i) {
            unsigned long long o = __shfl_xor(bKey[i], m, 64);
            if (o < bKey[i]) bKey[i] = o;
        }
    }
    if (tk == 0) {
#pragma unroll
        for (int i = 0; i < 8; ++i)
            atomicMin(&rowKey[n0 + tr * 8 + i], bKey[i]);
    }
}

// ---------------------------------------------------------------------------
// resolve: rowKey -> idx outputs
// ---------------------------------------------------------------------------
__global__ __launch_bounds__(256) void k_resolve(const unsigned long long* __restrict__ rowKey,
                                                 float* __restrict__ outIdx,
                                                 int* __restrict__ wsIdx) {
    int n = blockIdx.x * 256 + threadIdx.x;
    unsigned long long key = rowKey[n];
    int bi = (int)(unsigned int)(key & 0xFFFFFFFFULL);
    outIdx[n] = (float)bi;
    wsIdx[n]  = bi;
}

// ---------------------------------------------------------------------------
// epilogue — z_q gather, straight-through output, loss partial sums
// ---------------------------------------------------------------------------
__global__ __launch_bounds__(256) void k_epilogue(const float* __restrict__ z,
                                                  const float* __restrict__ e,
                                                  const int* __restrict__ wsIdx,
                                                  float* __restrict__ outZ,
                                                  float* __restrict__ lossAcc) {
    __shared__ float4 zq4[64][64];
    __shared__ int idxs[64];
    const int t = threadIdx.x;
    const int n0 = blockIdx.x * 64;
    const int b = n0 >> 10, nl0 = n0 & 1023;

    if (t < 64) idxs[t] = wsIdx[n0 + t];
    __syncthreads();

#pragma unroll
    for (int j = 0; j < 16; ++j) {
        int flat = j * 256 + t;
        int i  = flat >> 6;
        int c4 = flat & 63;
        float4 v = *(const float4*)(e + (size_t)idxs[i] * D_DIM + c4 * 4);
        zq4[i][c4 ^ (i & 7)] = v;
    }
    __syncthreads();

    const int i  = t & 63;
    const int dg = t >> 6;
    const float* zp = z    + (size_t)b * (D_DIM * 1024) + nl0 + i;
    float*       op = outZ + (size_t)b * (D_DIM * 1024) + nl0 + i;
    float s = 0.f;
#pragma unroll 4
    for (int c = 0; c < 16; ++c) {
        int c4 = dg * 16 + c;
        float4 q = zq4[i][c4 ^ (i & 7)];
        int d = c4 * 4;
        float zv, df;
        zv = zp[(size_t)(d + 0) * 1024]; df = q.x - zv; s = fmaf(df, df, s); op[(size_t)(d + 0) * 1024] = zv + df;
        zv = zp[(size_t)(d + 1) * 1024]; df = q.y - zv; s = fmaf(df, df, s); op[(size_t)(d + 1) * 1024] = zv + df;
        zv = zp[(size_t)(d + 2) * 1024]; df = q.z - zv; s = fmaf(df, df, s); op[(size_t)(d + 2) * 1024] = zv + df;
        zv = zp[(size_t)(d + 3) * 1024]; df = q.w - zv; s = fmaf(df, df, s); op[(size_t)(d + 3) * 1024] = zv + df;
    }
#pragma unroll
    for (int off = 32; off > 0; off >>= 1) s += __shfl_down(s, off, 64);
    if ((t & 63) == 0) atomicAdd(lossAcc, s);
}

__global__ void k_final(const float* __restrict__ lossAcc,
                        float* __restrict__ outLoss) {
    float m = lossAcc[0] * (1.0f / 8388608.0f);
    outLoss[0] = m + 0.25f * m;
}

// ---------------------------------------------------------------------------
extern "C" void kernel_launch(void* const* d_in, const int* in_sizes, int n_in,
                              void* d_out, int out_size, void* d_ws, size_t ws_size,
                              hipStream_t stream) {
    const float* z = (const float*)d_in[0];   // (32,256,32,32)
    const float* e = (const float*)d_in[1];   // (1024,256)
    float* out     = (float*)d_out;
    float* outIdx  = out + 8388608;
    float* outLoss = out + 8421376;

    float* z2      = (float*)d_ws;                         // 32768 f
    float* e2      = z2 + 32768;                           // 1024 f
    int*   wsIdx   = (int*)(e2 + 1024);                    // 32768 i
    float* lossAcc = (float*)(wsIdx + 32768);              // 1 f
    uintptr_t p = (uintptr_t)(lossAcc + 1);
    p = (p + 255) & ~(uintptr_t)255;
    unsigned long long* rowKey = (unsigned long long*)p;   // 32768 u64 = 256 KB
    float* et = (float*)(rowKey + 32768);                  // 262144 f = 1 MB

    hipMemsetAsync(lossAcc, 0, sizeof(float), stream);
    hipMemsetAsync(rowKey, 0xFF, 32768 * sizeof(unsigned long long), stream);
    k_z2<<<128, 256, 0, stream>>>(z, z2);
    k_e2<<<4, 256, 0, stream>>>(e, e2);
    k_tr<<<256, 256, 0, stream>>>(e, et);
    k_main<<<2048, 256, 0, stream>>>(z, et, z2, e2, rowKey);
    k_resolve<<<128, 256, 0, stream>>>(rowKey, outIdx, wsIdx);
    k_epilogue<<<512, 256, 0, stream>>>(z, e, wsIdx, out, lossAcc);
    k_final<<<1, 1, 0, stream>>>(lossAcc, outLoss);
}